// Round 1
// baseline (4372.968 us; speedup 1.0000x reference)
//
#include <hip/hip_runtime.h>
#include <math.h>

#define NB    64
#define DIM   256
#define TWOD  512
#define CNTE  1000
#define ETP   65   // eT row pad: bank = (k+n)%32 -> 2-way (free)

__global__ __launch_bounds__(256, 2) void encoder_attn_kernel(
    const int*   __restrict__ nei_rid,   // [B,64]
    const float* __restrict__ nei_e,     // [B,64,256]
    const float* __restrict__ nei_rw,    // [B,64]
    const int*   __restrict__ q_rid,     // [B]
    const float* __restrict__ w_r,       // [1001,256]
    const float* __restrict__ zq_w,      // [1000,256]
    const float* __restrict__ attn_W,    // [512,512] row-major [o][i]
    const float* __restrict__ attn_b,    // [512]
    const float* __restrict__ u_a_w,     // [512]
    const float* __restrict__ u_a_b,     // [1]
    float*       __restrict__ out)       // [B,256]
{
    __shared__ float eT[DIM * ETP];      // e_tr transposed [k][n], 66560 B
    __shared__ float zq_lds[DIM];
    __shared__ float ua_lds[TWOD];
    __shared__ float zpart[TWOD];
    __shared__ float red_ew[256];
    __shared__ float red_ww[256];
    __shared__ float pen[NB];
    __shared__ float attn_lds[NB];
    __shared__ float lg_scratch[4 * NB];

    const int b = blockIdx.x;
    const int t = threadIdx.x;
    const int n = t >> 2;     // neighbor handled in phase 1
    const int q = t & 3;      // k-quarter in phase 1

    // ---- stage z_q and u_a into LDS ----
    const int qr = q_rid[b];
    zq_lds[t]       = zq_w[(size_t)qr * DIM + t];
    ua_lds[t]       = u_a_w[t];
    ua_lds[t + 256] = u_a_w[t + 256];

    // ---- phase 1a: partial dots e.w and w.w (4 threads per neighbor) ----
    const int rid = nei_rid[b * NB + n];
    const float4* e4 = (const float4*)(nei_e + ((size_t)(b * NB + n)) * DIM) + q * 16;
    const float4* w4 = (const float4*)(w_r + (size_t)rid * DIM) + q * 16;
    float sew = 0.f, sww = 0.f;
    #pragma unroll
    for (int j = 0; j < 16; ++j) {
        float4 ev = e4[j], wv = w4[j];
        sew += ev.x * wv.x + ev.y * wv.y + ev.z * wv.z + ev.w * wv.w;
        sww += wv.x * wv.x + wv.y * wv.y + wv.z * wv.z + wv.w * wv.w;
    }
    red_ew[t] = sew;
    red_ww[t] = sww;
    if (q == 0) pen[n] = (rid == CNTE) ? 1e19f : 0.f;
    __syncthreads();

    // ---- phase 1b: projection coefficient, write e_tr transposed ----
    {
        float ew = red_ew[n * 4] + red_ew[n * 4 + 1] + red_ew[n * 4 + 2] + red_ew[n * 4 + 3];
        float ww = red_ww[n * 4] + red_ww[n * 4 + 1] + red_ww[n * 4 + 2] + red_ww[n * 4 + 3];
        float nc   = fmaxf(sqrtf(ww), 1e-12f);
        float coef = ew / (nc * nc);
        float maskf = (rid < CNTE) ? 1.f : 0.f;
        #pragma unroll
        for (int j = 0; j < 16; ++j) {
            float4 ev = e4[j], wv = w4[j];
            int k0 = q * 64 + j * 4;
            eT[(k0 + 0) * ETP + n] = (ev.x - coef * wv.x) * maskf;
            eT[(k0 + 1) * ETP + n] = (ev.y - coef * wv.y) * maskf;
            eT[(k0 + 2) * ETP + n] = (ev.z - coef * wv.z) * maskf;
            eT[(k0 + 3) * ETP + n] = (ev.w - coef * wv.w) * maskf;
        }
    }

    // ---- phase 2: zpart[o] = attn_b[o] + W[o][0:256] . z_q ----
    #pragma unroll
    for (int oo = 0; oo < 2; ++oo) {
        int o = t + oo * 256;
        const float4* wrow = (const float4*)(attn_W + (size_t)o * TWOD);
        const float4* zq4  = (const float4*)zq_lds;
        float acc = attn_b[o];
        #pragma unroll 16
        for (int j = 0; j < 64; ++j) {
            float4 wq = wrow[j];
            float4 zv = zq4[j];
            acc += wq.x * zv.x + wq.y * zv.y + wq.z * zv.z + wq.w * zv.w;
        }
        zpart[o] = acc;
    }
    __syncthreads();   // eT + zpart ready

    // ---- phase 3: GEMM (e-half of W) + tanh + u_a reduction ----
    const int wv_id = t >> 6;   // wave 0..3 -> o block of 128
    const int lane  = t & 63;   // = neighbor n
    float logit_part = 0.f;
    #pragma unroll 1
    for (int oc = 0; oc < 4; ++oc) {
        const int obase = wv_id * 128 + oc * 32;
        float acc[32];
        #pragma unroll
        for (int i = 0; i < 32; ++i) acc[i] = 0.f;
        #pragma unroll 1
        for (int kc = 0; kc < DIM; kc += 32) {
            float er[32];
            #pragma unroll
            for (int j = 0; j < 32; ++j) er[j] = eT[(kc + j) * ETP + lane];
            #pragma unroll
            for (int oi = 0; oi < 32; ++oi) {
                const float4* wrow = (const float4*)(attn_W + (size_t)(obase + oi) * TWOD + DIM) + (kc >> 2);
                #pragma unroll
                for (int jj = 0; jj < 8; ++jj) {
                    float4 wq = wrow[jj];   // wave-uniform address -> broadcast
                    acc[oi] += wq.x * er[jj * 4 + 0] + wq.y * er[jj * 4 + 1]
                             + wq.z * er[jj * 4 + 2] + wq.w * er[jj * 4 + 3];
                }
            }
        }
        #pragma unroll
        for (int oi = 0; oi < 32; ++oi) {
            int o = obase + oi;
            float h = tanhf(acc[oi] + zpart[o]);
            logit_part += ua_lds[o] * h;
        }
    }
    lg_scratch[wv_id * NB + lane] = logit_part;
    __syncthreads();

    // ---- phase 4: softmax over 64 neighbors (wave 0) ----
    if (t < NB) {
        float lgt = lg_scratch[t] + lg_scratch[NB + t] + lg_scratch[2 * NB + t]
                  + lg_scratch[3 * NB + t] + u_a_b[0] - pen[t];
        float m = lgt;
        #pragma unroll
        for (int off = 32; off > 0; off >>= 1) m = fmaxf(m, __shfl_xor(m, off));
        float ex = __expf(lgt - m);
        float s = ex;
        #pragma unroll
        for (int off = 32; off > 0; off >>= 1) s += __shfl_xor(s, off);
        attn_lds[t] = ex / s + nei_rw[b * NB + t];
    }
    __syncthreads();

    // ---- phase 5: out[b][k] = sum_n attn[n] * e_tr[n][k] ----
    float oacc = 0.f;
    #pragma unroll
    for (int nn = 0; nn < NB; ++nn)
        oacc += attn_lds[nn] * eT[t * ETP + nn];
    out[(size_t)b * DIM + t] = oacc;
}

extern "C" void kernel_launch(void* const* d_in, const int* in_sizes, int n_in,
                              void* d_out, int out_size, void* d_ws, size_t ws_size,
                              hipStream_t stream) {
    const int*   nei_rid = (const int*)  d_in[0];
    const float* nei_e   = (const float*)d_in[1];
    const float* nei_rw  = (const float*)d_in[2];
    const int*   q_rid   = (const int*)  d_in[3];
    const float* w_r     = (const float*)d_in[4];
    const float* zq_w    = (const float*)d_in[5];
    const float* attn_W  = (const float*)d_in[6];
    const float* attn_b  = (const float*)d_in[7];
    const float* u_a_w   = (const float*)d_in[8];
    const float* u_a_b   = (const float*)d_in[9];
    float* out = (float*)d_out;

    const int B = in_sizes[3];   // q_rid length = batch
    hipLaunchKernelGGL(encoder_attn_kernel, dim3(B), dim3(256), 0, stream,
                       nei_rid, nei_e, nei_rw, q_rid, w_r, zq_w,
                       attn_W, attn_b, u_a_w, u_a_b, out);
}